// Round 7
// baseline (239.073 us; speedup 1.0000x reference)
//
#include <hip/hip_runtime.h>
#include <hip/hip_bf16.h>
#include <math.h>

#define CH 128      // OUT_SIZE * HEADS
#define KIN 128     // IN_SIZE
#define FCAP 2560   // slab slots per 64-node bucket (mean 2048 +- 45, 11 sigma headroom)
#define FPAD 3344   // FCAP + 256 keys * 3 max pad (768) + spare
#define EB 8192     // edges per k_bucket block (196 blocks; R4-proven best)

typedef __attribute__((ext_vector_type(8))) short short8;   // 8 bf16 (4 VGPRs)
typedef __attribute__((ext_vector_type(4))) float f32x4;    // MFMA acc

__device__ __forceinline__ unsigned short f2bf(float x) {
    __hip_bfloat16 h = __float2bfloat16(x);
    return *reinterpret_cast<unsigned short*>(&h);
}

// ------- K1: MFMA gemm: Zp16 = bf16(Z @ W^T + b), fused el/er epilogue -------
// Also zeroes gcnt (block 0) so no separate memset dispatch is needed.
#define AS 136   // padded LDS stride (halfwords) per row
__global__ __launch_bounds__(256) void k_gemm(const float* __restrict__ Z,
                                              const float* __restrict__ W,
                                              const float* __restrict__ b,
                                              const float* __restrict__ al,
                                              const float* __restrict__ ar,
                                              unsigned short* __restrict__ Zp16,
                                              float* __restrict__ el,
                                              float* __restrict__ er,
                                              int* __restrict__ gcnt,
                                              int N, int NBK)
{
    __shared__ unsigned short lA[64 * AS];
    __shared__ unsigned short lB[128 * AS];
    const int tid = threadIdx.x;
    const int nb0 = blockIdx.x * 64;

    if (blockIdx.x == 0) {
        for (int i = tid; i < 2 * NBK; i += 256) gcnt[i] = 0;
    }

#pragma unroll
    for (int i = 0; i < 8; i++) {
        int slot = tid + i * 256;
        int row  = slot >> 5;
        int kq   = (slot & 31) * 4;
        int gn   = nb0 + row; if (gn >= N) gn = N - 1;
        float4 v = *(const float4*)(Z + (size_t)gn * KIN + kq);
        unsigned lo = ((unsigned)f2bf(v.y) << 16) | f2bf(v.x);
        unsigned hi = ((unsigned)f2bf(v.w) << 16) | f2bf(v.z);
        uint2 pk; pk.x = lo; pk.y = hi;
        *(uint2*)(&lA[row * AS + kq]) = pk;
    }
#pragma unroll
    for (int i = 0; i < 16; i++) {
        int slot = tid + i * 256;
        int n    = slot >> 5;
        int kq   = (slot & 31) * 4;
        float4 v = *(const float4*)(W + (size_t)n * KIN + kq);
        unsigned lo = ((unsigned)f2bf(v.y) << 16) | f2bf(v.x);
        unsigned hi = ((unsigned)f2bf(v.w) << 16) | f2bf(v.z);
        uint2 pk; pk.x = lo; pk.y = hi;
        *(uint2*)(&lB[n * AS + kq]) = pk;
    }
    __syncthreads();

    const int wv   = tid >> 6;
    const int lane = tid & 63;
    const int r16  = lane & 15;
    const int quad = lane >> 4;

    f32x4 acc[8];
#pragma unroll
    for (int t = 0; t < 8; t++) { acc[t][0] = 0.f; acc[t][1] = 0.f; acc[t][2] = 0.f; acc[t][3] = 0.f; }

    const unsigned short* pa = lA + (wv * 16 + r16) * AS;
#pragma unroll
    for (int kk = 0; kk < 4; kk++) {
        short8 af = *(const short8*)(pa + kk * 32 + quad * 8);
#pragma unroll
        for (int t = 0; t < 8; t++) {
            short8 bf = *(const short8*)(lB + (16 * t + r16) * AS + kk * 32 + quad * 8);
            acc[t] = __builtin_amdgcn_mfma_f32_16x16x32_bf16(af, bf, acc[t], 0, 0, 0);
        }
    }

    float bias[8], alv[8], arv[8];
#pragma unroll
    for (int t = 0; t < 8; t++) {
        bias[t] = b[16 * t + r16];
        alv[t]  = al[16 * t + r16];
        arv[t]  = ar[16 * t + r16];
    }
#pragma unroll
    for (int t = 0; t < 8; t++) {
#pragma unroll
        for (int reg = 0; reg < 4; reg++) acc[t][reg] += bias[t];
    }

    float ev[4], rv[4];
#pragma unroll
    for (int reg = 0; reg < 4; reg++) {
        float se = 0.f, sr = 0.f;
#pragma unroll
        for (int t = 0; t < 8; t++) { se += acc[t][reg] * alv[t]; sr += acc[t][reg] * arv[t]; }
        se += __shfl_xor(se, 4, 64); se += __shfl_xor(se, 8, 64);
        sr += __shfl_xor(sr, 4, 64); sr += __shfl_xor(sr, 8, 64);
        ev[reg] = se; rv[reg] = sr;
    }
    if (r16 < 4) {
        int h = r16;
#pragma unroll
        for (int reg = 0; reg < 4; reg++) {
            int gn = nb0 + wv * 16 + quad * 4 + reg;
            if (gn < N) {
                el[(size_t)gn * 4 + h] = ev[reg];
                er[(size_t)gn * 4 + h] = rv[reg];
            }
        }
    }

    __syncthreads();
#pragma unroll
    for (int t = 0; t < 8; t++) {
#pragma unroll
        for (int reg = 0; reg < 4; reg++) {
            int rrow = wv * 16 + quad * 4 + reg;
            lA[rrow * AS + 16 * t + r16] = f2bf(acc[t][reg]);
        }
    }
    __syncthreads();
    {
        int row  = tid >> 2;
        int col0 = (tid & 3) * 32;
        int gn   = nb0 + row;
        if (gn < N) {
            const unsigned short* sp = lA + row * AS + col0;
            uint4 v0 = *(const uint4*)(sp);
            uint4 v1 = *(const uint4*)(sp + 8);
            uint4 v2 = *(const uint4*)(sp + 16);
            uint4 v3 = *(const uint4*)(sp + 24);
            uint4* dp = (uint4*)(Zp16 + (size_t)gn * CH + col0);
            dp[0] = v0; dp[1] = v1; dp[2] = v2; dp[3] = v3;
        }
    }
}

// ------- K2: dual-side bucket scatter, single pass (8 edges/thread in registers) -------
// payload: (node&63)<<26 | other_node ; slab for (side,bucket) i at C[i*FCAP ...]
__global__ __launch_bounds__(1024) void k_bucket(const int* __restrict__ idx,
                                                 int* __restrict__ gcnt,
                                                 unsigned* __restrict__ C,
                                                 int E, int NBK)
{
    __shared__ int cnt[2048];
    __shared__ int lbase[2048];
    const int t = threadIdx.x;
    const int nb2 = 2 * NBK;
    for (int i = t; i < nb2; i += 1024) cnt[i] = 0;
    __syncthreads();
    const int lo = blockIdx.x * EB;
    const int hi = min(lo + EB, E);

    int s[8], d[8], rs[8], rd[8];
    int nv = 0;
    {
        int base = lo + 8 * t;
        if (base < hi) {
            nv = hi - base; if (nv > 8) nv = 8;
            if (nv == 8) {
                int4 sa = *(const int4*)(idx + base);
                int4 sb = *(const int4*)(idx + base + 4);
                int4 da = *(const int4*)(idx + E + base);
                int4 db = *(const int4*)(idx + E + base + 4);
                s[0] = sa.x; s[1] = sa.y; s[2] = sa.z; s[3] = sa.w;
                s[4] = sb.x; s[5] = sb.y; s[6] = sb.z; s[7] = sb.w;
                d[0] = da.x; d[1] = da.y; d[2] = da.z; d[3] = da.w;
                d[4] = db.x; d[5] = db.y; d[6] = db.z; d[7] = db.w;
            } else {
#pragma unroll
                for (int k = 0; k < 8; k++) {
                    if (k < nv) { s[k] = idx[base + k]; d[k] = idx[E + base + k]; }
                }
            }
#pragma unroll
            for (int k = 0; k < 8; k++) {
                if (k < nv) {
                    rs[k] = atomicAdd(&cnt[s[k] >> 6], 1);
                    rd[k] = atomicAdd(&cnt[NBK + (d[k] >> 6)], 1);
                }
            }
        }
    }
    __syncthreads();
    for (int i = t; i < nb2; i += 1024) {
        int v = cnt[i];
        lbase[i] = v ? atomicAdd(&gcnt[i], v) : 0;
    }
    __syncthreads();
#pragma unroll
    for (int k = 0; k < 8; k++) {
        if (k < nv) {
            int bs = s[k] >> 6;
            int p  = lbase[bs] + rs[k];
            if (p < FCAP)
                C[(size_t)bs * FCAP + p] = ((unsigned)(s[k] & 63) << 26) | (unsigned)d[k];
            int bd = NBK + (d[k] >> 6);
            p = lbase[bd] + rd[k];
            if (p < FCAP)
                C[(size_t)bd * FCAP + p] = ((unsigned)(d[k] & 63) << 26) | (unsigned)s[k];
        }
    }
}

// ------- K3: dst-side softmax denominators via sort + segmented reduce (no atomics) -------
// Output esv[node*8] = (er0, 1/s0, er1, 1/s1, er2, 1/s2, er3, 1/s3).
__global__ __launch_bounds__(1024) void k_soft(const unsigned* __restrict__ C,
                                               const int* __restrict__ gcnt,
                                               const float* __restrict__ el,
                                               const float* __restrict__ er,
                                               float* __restrict__ esv, int N, int NBK)
{
    __shared__ float4 sexp[FCAP];   // 40 KB
    __shared__ float4 fer[64];
    __shared__ int cnt[64], loffs[64];
    const int i = blockIdx.x;
    const int t = threadIdx.x;
    int count = gcnt[NBK + i]; if (count > FCAP) count = FCAP;
    const unsigned* slab = C + (size_t)(NBK + i) * FCAP;
    if (t < 64) {
        cnt[t] = 0;
        int node = i * 64 + t;
        float4 e;
        if (node < N) e = *(const float4*)(er + (size_t)node * 4);
        else { e.x = 0.f; e.y = 0.f; e.z = 0.f; e.w = 0.f; }
        fer[t] = e;
    }
    __syncthreads();
    unsigned pv[4]; int rk[4];
    int nv = 0;
    {
        int base = 4 * t;
        if (base < count) {
            nv = count - base; if (nv > 4) nv = 4;
            if (nv == 4) {
                uint4 u = *(const uint4*)(slab + base);
                pv[0] = u.x; pv[1] = u.y; pv[2] = u.z; pv[3] = u.w;
            } else {
#pragma unroll
                for (int k = 0; k < 4; k++) { if (k < nv) pv[k] = slab[base + k]; }
            }
#pragma unroll
            for (int k = 0; k < 4; k++) {
                if (k < nv) rk[k] = atomicAdd(&cnt[pv[k] >> 26], 1);
            }
        }
    }
    __syncthreads();
    if (t < 64) {
        int v = cnt[t], inc = v;
#pragma unroll
        for (int mm = 1; mm < 64; mm <<= 1) {
            int u = __shfl_up(inc, mm, 64);
            if (t >= mm) inc += u;
        }
        loffs[t] = inc - v;
    }
    __syncthreads();
#pragma unroll
    for (int k = 0; k < 4; k++) {
        if (k < nv) {
            unsigned v = pv[k];
            int d6 = v >> 26;
            unsigned src = v & 0xFFFFu;
            float4 le = *(const float4*)(el + (size_t)src * 4);
            float4 re = fer[d6];
            float a0 = le.x + re.x, a1 = le.y + re.y;
            float a2 = le.z + re.z, a3 = le.w + re.w;
            a0 = fmaxf(a0, 0.01f * a0); a1 = fmaxf(a1, 0.01f * a1);
            a2 = fmaxf(a2, 0.01f * a2); a3 = fmaxf(a3, 0.01f * a3);
            float4 e4;
            e4.x = __expf(a0); e4.y = __expf(a1);
            e4.z = __expf(a2); e4.w = __expf(a3);
            sexp[loffs[d6] + rk[k]] = e4;
        }
    }
    __syncthreads();
    {
        const int ln  = t >> 4;
        const int l16 = t & 15;
        const int st  = loffs[ln];
        const int en  = st + cnt[ln];
        float4 sum; sum.x = 0.f; sum.y = 0.f; sum.z = 0.f; sum.w = 0.f;
        for (int j = st + l16; j < en; j += 16) {
            float4 e = sexp[j];
            sum.x += e.x; sum.y += e.y; sum.z += e.z; sum.w += e.w;
        }
#pragma unroll
        for (int mm = 1; mm < 16; mm <<= 1) {
            sum.x += __shfl_xor(sum.x, mm, 64);
            sum.y += __shfl_xor(sum.y, mm, 64);
            sum.z += __shfl_xor(sum.z, mm, 64);
            sum.w += __shfl_xor(sum.w, mm, 64);
        }
        int node = i * 64 + ln;
        if (l16 == 0 && node < N) {
            float4 re = fer[ln];
            float4 w0; w0.x = re.x; w0.y = (sum.x > 0.f) ? 1.0f / sum.x : 0.f;
                       w0.z = re.y; w0.w = (sum.y > 0.f) ? 1.0f / sum.y : 0.f;
            float4 w1; w1.x = re.z; w1.y = (sum.z > 0.f) ? 1.0f / sum.z : 0.f;
                       w1.z = re.w; w1.w = (sum.w > 0.f) ? 1.0f / sum.w : 0.f;
            *(float4*)(esv + (size_t)node * 8)     = w0;
            *(float4*)(esv + (size_t)node * 8 + 4) = w1;
        }
    }
}

// ------- K4: dst-quadrant time-partitioned gather -------
// Sort key = (node&63)*4 + (dst>>14): per-node edges grouped into 4 dst-quadrants
// (<=16384 rows x 256B ~ 4.2MB each ~ one XCD L2). Phase 4 sweeps quadrants
// OUTERMOST so all waves/blocks touch the same ~4MB of Zp16 in each time window.
// launch_bounds(1024,4): VGPR cap 128 so the 4 persistent acc arrays live in
// registers (R6's (1024,8) capped at 64 -> 50MB spill traffic, the regression).
__global__ __launch_bounds__(1024, 4) void k_gather(const unsigned* __restrict__ C,
                                                    const int* __restrict__ gcnt,
                                                    const float* __restrict__ el,
                                                    const float* __restrict__ esv,
                                                    const unsigned short* __restrict__ Zp16,
                                                    float* __restrict__ out, int N)
{
    __shared__ uint4  meta[FPAD];   // x = dst<<8 (row byte offset), y = w01, z = w23
    __shared__ float4 fel[64];
    __shared__ int cnt[256], loffs[256];
    const int i = blockIdx.x;
    const int t = threadIdx.x;
    int count = gcnt[i]; if (count > FCAP) count = FCAP;
    const unsigned* slab = C + (size_t)i * FCAP;
    if (t < 64) {
        int node = i * 64 + t;
        float4 e;
        if (node < N) e = *(const float4*)(el + (size_t)node * 4);
        else { e.x = 0.f; e.y = 0.f; e.z = 0.f; e.w = 0.f; }
        fel[t] = e;
    }
    if (t < 256) cnt[t] = 0;
    for (int j = t; j < FPAD; j += 1024) {
        uint4 zz; zz.x = 0; zz.y = 0; zz.z = 0; zz.w = 0;
        meta[j] = zz;
    }
    __syncthreads();
    // phase 1: single-pass rank+histogram over 256 (node, dst-quadrant) keys
    unsigned pv[4]; int rk[4], ky[4];
    int nv = 0;
    {
        int base = 4 * t;
        if (base < count) {
            nv = count - base; if (nv > 4) nv = 4;
            if (nv == 4) {
                uint4 u = *(const uint4*)(slab + base);
                pv[0] = u.x; pv[1] = u.y; pv[2] = u.z; pv[3] = u.w;
            } else {
#pragma unroll
                for (int k = 0; k < 4; k++) { if (k < nv) pv[k] = slab[base + k]; }
            }
#pragma unroll
            for (int k = 0; k < 4; k++) {
                if (k < nv) {
                    ky[k] = (int)(((pv[k] >> 26) << 2) | ((pv[k] & 0xFFFFu) >> 14));
                    rk[k] = atomicAdd(&cnt[ky[k]], 1);
                }
            }
        }
    }
    __syncthreads();
    // phase 2: exclusive scan over 256 counts, each rounded to multiple of 4 (wave 0)
    if (t < 64) {
        int b = t * 4;
        int c0 = (cnt[b]     + 3) & ~3;
        int c1 = (cnt[b + 1] + 3) & ~3;
        int c2 = (cnt[b + 2] + 3) & ~3;
        int c3 = (cnt[b + 3] + 3) & ~3;
        int s = c0 + c1 + c2 + c3;
        int inc = s;
#pragma unroll
        for (int mm = 1; mm < 64; mm <<= 1) {
            int u = __shfl_up(inc, mm, 64);
            if (t >= mm) inc += u;
        }
        int pre = inc - s;
        loffs[b]     = pre;
        loffs[b + 1] = pre + c0;
        loffs[b + 2] = pre + c0 + c1;
        loffs[b + 3] = pre + c0 + c1 + c2;
    }
    __syncthreads();
    // phase 3: weight computation + scatter into meta (from registers)
#pragma unroll
    for (int k = 0; k < 4; k++) {
        if (k < nv) {
            unsigned v = pv[k];
            unsigned dst = v & 0xFFFFu;
            int p = loffs[ky[k]] + rk[k];
            float4 ed = fel[v >> 26];
            float4 e0 = *(const float4*)(esv + (size_t)dst * 8);
            float4 e1 = *(const float4*)(esv + (size_t)dst * 8 + 4);
            float a0 = ed.x + e0.x, a1 = ed.y + e0.z;
            float a2 = ed.z + e1.x, a3 = ed.w + e1.z;
            a0 = fmaxf(a0, 0.01f * a0); a1 = fmaxf(a1, 0.01f * a1);
            a2 = fmaxf(a2, 0.01f * a2); a3 = fmaxf(a3, 0.01f * a3);
            float t0 = __expf(a0) * e0.y;
            float t1 = __expf(a1) * e0.w;
            float t2 = __expf(a2) * e1.y;
            float t3 = __expf(a3) * e1.w;
            unsigned u0 = __float_as_uint(t0) + 0x8000u;
            unsigned u1 = __float_as_uint(t1) + 0x8000u;
            unsigned u2 = __float_as_uint(t2) + 0x8000u;
            unsigned u3 = __float_as_uint(t3) + 0x8000u;
            uint4 mr;
            mr.x = dst << 8;
            mr.y = (u0 >> 16) | (u1 & 0xffff0000u);
            mr.z = (u2 >> 16) | (u3 & 0xffff0000u);
            mr.w = 0;
            meta[p] = mr;
        }
    }
    __syncthreads();
    // phase 4: quadrant-outermost gather; wave w owns nodes w*4..w*4+3, quarter q
    // processes edge j=st+q (step 4) of the current (node, quadrant) segment.
    const int wave = t >> 6;
    const int q    = (t >> 4) & 3;
    const int m    = t & 15;
    const unsigned vm = (unsigned)m * 16u;
    const char* zb = (const char*)Zp16;
#define GB(ACC, J) { \
        uint4 mu = meta[(J)]; \
        uint4 z  = *(const uint4*)(zb + (size_t)(mu.x + vm)); \
        float wxl = __uint_as_float(mu.y << 16); \
        float wxh = __uint_as_float(mu.y & 0xffff0000u); \
        float wyl = __uint_as_float(mu.z << 16); \
        float wyh = __uint_as_float(mu.z & 0xffff0000u); \
        ACC[0] = fmaf(wxl, __uint_as_float(z.x << 16),         ACC[0]); \
        ACC[1] = fmaf(wxh, __uint_as_float(z.x & 0xffff0000u), ACC[1]); \
        ACC[2] = fmaf(wyl, __uint_as_float(z.y << 16),         ACC[2]); \
        ACC[3] = fmaf(wyh, __uint_as_float(z.y & 0xffff0000u), ACC[3]); \
        ACC[4] = fmaf(wxl, __uint_as_float(z.z << 16),         ACC[4]); \
        ACC[5] = fmaf(wxh, __uint_as_float(z.z & 0xffff0000u), ACC[5]); \
        ACC[6] = fmaf(wyl, __uint_as_float(z.w << 16),         ACC[6]); \
        ACC[7] = fmaf(wyh, __uint_as_float(z.w & 0xffff0000u), ACC[7]); \
    }
#define SEGLOOP(ACC, KN) { \
        int key = ((wave * 4 + (KN)) << 2) | seg; \
        int st  = loffs[key]; \
        int en  = st + ((cnt[key] + 3) & ~3); \
        for (int j = st + q; j < en; j += 4) GB(ACC, j); \
    }
    float acc0[8], acc1[8], acc2[8], acc3[8];
#pragma unroll
    for (int rr = 0; rr < 8; rr++) { acc0[rr] = 0.f; acc1[rr] = 0.f; acc2[rr] = 0.f; acc3[rr] = 0.f; }
    for (int seg = 0; seg < 4; seg++) {
        SEGLOOP(acc0, 0);
        SEGLOOP(acc1, 1);
        SEGLOOP(acc2, 2);
        SEGLOOP(acc3, 3);
    }
#undef SEGLOOP
#undef GB
#pragma unroll
    for (int rr = 0; rr < 8; rr++) {
        acc0[rr] += __shfl_xor(acc0[rr], 16, 64); acc0[rr] += __shfl_xor(acc0[rr], 32, 64);
        acc1[rr] += __shfl_xor(acc1[rr], 16, 64); acc1[rr] += __shfl_xor(acc1[rr], 32, 64);
        acc2[rr] += __shfl_xor(acc2[rr], 16, 64); acc2[rr] += __shfl_xor(acc2[rr], 32, 64);
        acc3[rr] += __shfl_xor(acc3[rr], 16, 64); acc3[rr] += __shfl_xor(acc3[rr], 32, 64);
    }
    {
        int node = i * 64 + wave * 4 + q;
        if (node < N) {
            float4 r0, r1;
            if (q == 0) {
                r0.x = acc0[0]; r0.y = acc0[1]; r0.z = acc0[2]; r0.w = acc0[3];
                r1.x = acc0[4]; r1.y = acc0[5]; r1.z = acc0[6]; r1.w = acc0[7];
            } else if (q == 1) {
                r0.x = acc1[0]; r0.y = acc1[1]; r0.z = acc1[2]; r0.w = acc1[3];
                r1.x = acc1[4]; r1.y = acc1[5]; r1.z = acc1[6]; r1.w = acc1[7];
            } else if (q == 2) {
                r0.x = acc2[0]; r0.y = acc2[1]; r0.z = acc2[2]; r0.w = acc2[3];
                r1.x = acc2[4]; r1.y = acc2[5]; r1.z = acc2[6]; r1.w = acc2[7];
            } else {
                r0.x = acc3[0]; r0.y = acc3[1]; r0.z = acc3[2]; r0.w = acc3[3];
                r1.x = acc3[4]; r1.y = acc3[5]; r1.z = acc3[6]; r1.w = acc3[7];
            }
            float4* dp = (float4*)(out + (size_t)node * CH + m * 8);
            dp[0] = r0; dp[1] = r1;
        }
    }
}

static inline char* align16(char* p) {
    return (char*)(((uintptr_t)p + 15) & ~(uintptr_t)15);
}

extern "C" void kernel_launch(void* const* d_in, const int* in_sizes, int n_in,
                              void* d_out, int out_size, void* d_ws, size_t ws_size,
                              hipStream_t stream)
{
    const int*   idx = (const int*)d_in[0];
    const float* Z   = (const float*)d_in[2];
    const float* W   = (const float*)d_in[3];
    const float* b   = (const float*)d_in[4];
    const float* al  = (const float*)d_in[5];
    const float* ar  = (const float*)d_in[6];
    float* out = (float*)d_out;

    const int E = in_sizes[0] / 2;
    const int N = in_sizes[2] / KIN;
    const int NBK = (N + 63) >> 6;      // 64-node buckets (<= 1024)

    char* p = (char*)d_ws;
    unsigned short* Zp16 = (unsigned short*)p;  p = align16(p + sizeof(unsigned short) * (size_t)N * CH);
    float* el  = (float*)p;              p = align16(p + sizeof(float) * (size_t)N * 4);
    float* er  = (float*)p;              p = align16(p + sizeof(float) * (size_t)N * 4);
    float* esv = (float*)p;              p = align16(p + sizeof(float) * (size_t)N * 8);
    int* gcnt  = (int*)p;                p = align16(p + sizeof(int) * (size_t)2 * NBK);
    unsigned* C = (unsigned*)p;          p = align16(p + sizeof(unsigned) * (size_t)2 * NBK * FCAP);

    k_gemm  <<<NBK, 256, 0, stream>>>(Z, W, b, al, ar, Zp16, el, er, gcnt, N, NBK);
    k_bucket<<<(E + EB - 1) / EB, 1024, 0, stream>>>(idx, gcnt, C, E, NBK);
    k_soft  <<<NBK, 1024, 0, stream>>>(C, gcnt, el, er, esv, N, NBK);
    k_gather<<<NBK, 1024, 0, stream>>>(C, gcnt, el, esv, Zp16, out, N);
}

// Round 8
// 208.271 us; speedup vs baseline: 1.1479x; 1.1479x over previous
//
#include <hip/hip_runtime.h>
#include <hip/hip_bf16.h>
#include <math.h>

#define CH 128      // OUT_SIZE * HEADS
#define KIN 128     // IN_SIZE
#define FCAP 2560   // slab slots per 64-node bucket (mean 2048 +- 45, 11 sigma headroom)
#define FPAD 3072   // FCAP + 64 nodes * 7 max pad (448) -> 3008 <= 3072
#define EB 8192     // edges per k_bucket block (196 blocks; R4-proven best)

typedef __attribute__((ext_vector_type(8))) short short8;   // 8 bf16 (4 VGPRs)
typedef __attribute__((ext_vector_type(4))) float f32x4;    // MFMA acc

__device__ __forceinline__ unsigned short f2bf(float x) {
    __hip_bfloat16 h = __float2bfloat16(x);
    return *reinterpret_cast<unsigned short*>(&h);
}

// ------- K1: MFMA gemm: Zp16 = bf16(Z @ W^T + b), fused el/er epilogue -------
// Also zeroes gcnt (block 0) so no separate memset dispatch is needed.
#define AS 136   // padded LDS stride (halfwords) per row
__global__ __launch_bounds__(256) void k_gemm(const float* __restrict__ Z,
                                              const float* __restrict__ W,
                                              const float* __restrict__ b,
                                              const float* __restrict__ al,
                                              const float* __restrict__ ar,
                                              unsigned short* __restrict__ Zp16,
                                              float* __restrict__ el,
                                              float* __restrict__ er,
                                              int* __restrict__ gcnt,
                                              int N, int NBK)
{
    __shared__ unsigned short lA[64 * AS];
    __shared__ unsigned short lB[128 * AS];
    const int tid = threadIdx.x;
    const int nb0 = blockIdx.x * 64;

    if (blockIdx.x == 0) {
        for (int i = tid; i < 2 * NBK; i += 256) gcnt[i] = 0;
    }

#pragma unroll
    for (int i = 0; i < 8; i++) {
        int slot = tid + i * 256;
        int row  = slot >> 5;
        int kq   = (slot & 31) * 4;
        int gn   = nb0 + row; if (gn >= N) gn = N - 1;
        float4 v = *(const float4*)(Z + (size_t)gn * KIN + kq);
        unsigned lo = ((unsigned)f2bf(v.y) << 16) | f2bf(v.x);
        unsigned hi = ((unsigned)f2bf(v.w) << 16) | f2bf(v.z);
        uint2 pk; pk.x = lo; pk.y = hi;
        *(uint2*)(&lA[row * AS + kq]) = pk;
    }
#pragma unroll
    for (int i = 0; i < 16; i++) {
        int slot = tid + i * 256;
        int n    = slot >> 5;
        int kq   = (slot & 31) * 4;
        float4 v = *(const float4*)(W + (size_t)n * KIN + kq);
        unsigned lo = ((unsigned)f2bf(v.y) << 16) | f2bf(v.x);
        unsigned hi = ((unsigned)f2bf(v.w) << 16) | f2bf(v.z);
        uint2 pk; pk.x = lo; pk.y = hi;
        *(uint2*)(&lB[n * AS + kq]) = pk;
    }
    __syncthreads();

    const int wv   = tid >> 6;
    const int lane = tid & 63;
    const int r16  = lane & 15;
    const int quad = lane >> 4;

    f32x4 acc[8];
#pragma unroll
    for (int t = 0; t < 8; t++) { acc[t][0] = 0.f; acc[t][1] = 0.f; acc[t][2] = 0.f; acc[t][3] = 0.f; }

    const unsigned short* pa = lA + (wv * 16 + r16) * AS;
#pragma unroll
    for (int kk = 0; kk < 4; kk++) {
        short8 af = *(const short8*)(pa + kk * 32 + quad * 8);
#pragma unroll
        for (int t = 0; t < 8; t++) {
            short8 bf = *(const short8*)(lB + (16 * t + r16) * AS + kk * 32 + quad * 8);
            acc[t] = __builtin_amdgcn_mfma_f32_16x16x32_bf16(af, bf, acc[t], 0, 0, 0);
        }
    }

    float bias[8], alv[8], arv[8];
#pragma unroll
    for (int t = 0; t < 8; t++) {
        bias[t] = b[16 * t + r16];
        alv[t]  = al[16 * t + r16];
        arv[t]  = ar[16 * t + r16];
    }
#pragma unroll
    for (int t = 0; t < 8; t++) {
#pragma unroll
        for (int reg = 0; reg < 4; reg++) acc[t][reg] += bias[t];
    }

    float ev[4], rv[4];
#pragma unroll
    for (int reg = 0; reg < 4; reg++) {
        float se = 0.f, sr = 0.f;
#pragma unroll
        for (int t = 0; t < 8; t++) { se += acc[t][reg] * alv[t]; sr += acc[t][reg] * arv[t]; }
        se += __shfl_xor(se, 4, 64); se += __shfl_xor(se, 8, 64);
        sr += __shfl_xor(sr, 4, 64); sr += __shfl_xor(sr, 8, 64);
        ev[reg] = se; rv[reg] = sr;
    }
    if (r16 < 4) {
        int h = r16;
#pragma unroll
        for (int reg = 0; reg < 4; reg++) {
            int gn = nb0 + wv * 16 + quad * 4 + reg;
            if (gn < N) {
                el[(size_t)gn * 4 + h] = ev[reg];
                er[(size_t)gn * 4 + h] = rv[reg];
            }
        }
    }

    __syncthreads();
#pragma unroll
    for (int t = 0; t < 8; t++) {
#pragma unroll
        for (int reg = 0; reg < 4; reg++) {
            int rrow = wv * 16 + quad * 4 + reg;
            lA[rrow * AS + 16 * t + r16] = f2bf(acc[t][reg]);
        }
    }
    __syncthreads();
    {
        int row  = tid >> 2;
        int col0 = (tid & 3) * 32;
        int gn   = nb0 + row;
        if (gn < N) {
            const unsigned short* sp = lA + row * AS + col0;
            uint4 v0 = *(const uint4*)(sp);
            uint4 v1 = *(const uint4*)(sp + 8);
            uint4 v2 = *(const uint4*)(sp + 16);
            uint4 v3 = *(const uint4*)(sp + 24);
            uint4* dp = (uint4*)(Zp16 + (size_t)gn * CH + col0);
            dp[0] = v0; dp[1] = v1; dp[2] = v2; dp[3] = v3;
        }
    }
}

// ------- K2: dual-side bucket scatter, single pass (8 edges/thread in registers) -------
// payload: (node&63)<<26 | other_node ; slab for (side,bucket) i at C[i*FCAP ...]
__global__ __launch_bounds__(1024) void k_bucket(const int* __restrict__ idx,
                                                 int* __restrict__ gcnt,
                                                 unsigned* __restrict__ C,
                                                 int E, int NBK)
{
    __shared__ int cnt[2048];
    __shared__ int lbase[2048];
    const int t = threadIdx.x;
    const int nb2 = 2 * NBK;
    for (int i = t; i < nb2; i += 1024) cnt[i] = 0;
    __syncthreads();
    const int lo = blockIdx.x * EB;
    const int hi = min(lo + EB, E);

    int s[8], d[8], rs[8], rd[8];
    int nv = 0;
    {
        int base = lo + 8 * t;
        if (base < hi) {
            nv = hi - base; if (nv > 8) nv = 8;
            if (nv == 8) {
                int4 sa = *(const int4*)(idx + base);
                int4 sb = *(const int4*)(idx + base + 4);
                int4 da = *(const int4*)(idx + E + base);
                int4 db = *(const int4*)(idx + E + base + 4);
                s[0] = sa.x; s[1] = sa.y; s[2] = sa.z; s[3] = sa.w;
                s[4] = sb.x; s[5] = sb.y; s[6] = sb.z; s[7] = sb.w;
                d[0] = da.x; d[1] = da.y; d[2] = da.z; d[3] = da.w;
                d[4] = db.x; d[5] = db.y; d[6] = db.z; d[7] = db.w;
            } else {
#pragma unroll
                for (int k = 0; k < 8; k++) {
                    if (k < nv) { s[k] = idx[base + k]; d[k] = idx[E + base + k]; }
                }
            }
#pragma unroll
            for (int k = 0; k < 8; k++) {
                if (k < nv) {
                    rs[k] = atomicAdd(&cnt[s[k] >> 6], 1);
                    rd[k] = atomicAdd(&cnt[NBK + (d[k] >> 6)], 1);
                }
            }
        }
    }
    __syncthreads();
    for (int i = t; i < nb2; i += 1024) {
        int v = cnt[i];
        lbase[i] = v ? atomicAdd(&gcnt[i], v) : 0;
    }
    __syncthreads();
#pragma unroll
    for (int k = 0; k < 8; k++) {
        if (k < nv) {
            int bs = s[k] >> 6;
            int p  = lbase[bs] + rs[k];
            if (p < FCAP)
                C[(size_t)bs * FCAP + p] = ((unsigned)(s[k] & 63) << 26) | (unsigned)d[k];
            int bd = NBK + (d[k] >> 6);
            p = lbase[bd] + rd[k];
            if (p < FCAP)
                C[(size_t)bd * FCAP + p] = ((unsigned)(d[k] & 63) << 26) | (unsigned)s[k];
        }
    }
}

// ------- K3: dst-side softmax denominators via sort + segmented reduce (no atomics) -------
// Output esv[node*8] = (er0, 1/s0, er1, 1/s1, er2, 1/s2, er3, 1/s3).
__global__ __launch_bounds__(1024) void k_soft(const unsigned* __restrict__ C,
                                               const int* __restrict__ gcnt,
                                               const float* __restrict__ el,
                                               const float* __restrict__ er,
                                               float* __restrict__ esv, int N, int NBK)
{
    __shared__ float4 sexp[FCAP];   // 40 KB
    __shared__ float4 fer[64];
    __shared__ int cnt[64], loffs[64];
    const int i = blockIdx.x;
    const int t = threadIdx.x;
    int count = gcnt[NBK + i]; if (count > FCAP) count = FCAP;
    const unsigned* slab = C + (size_t)(NBK + i) * FCAP;
    if (t < 64) {
        cnt[t] = 0;
        int node = i * 64 + t;
        float4 e;
        if (node < N) e = *(const float4*)(er + (size_t)node * 4);
        else { e.x = 0.f; e.y = 0.f; e.z = 0.f; e.w = 0.f; }
        fer[t] = e;
    }
    __syncthreads();
    unsigned pv[4]; int rk[4];
    int nv = 0;
    {
        int base = 4 * t;
        if (base < count) {
            nv = count - base; if (nv > 4) nv = 4;
            if (nv == 4) {
                uint4 u = *(const uint4*)(slab + base);
                pv[0] = u.x; pv[1] = u.y; pv[2] = u.z; pv[3] = u.w;
            } else {
#pragma unroll
                for (int k = 0; k < 4; k++) { if (k < nv) pv[k] = slab[base + k]; }
            }
#pragma unroll
            for (int k = 0; k < 4; k++) {
                if (k < nv) rk[k] = atomicAdd(&cnt[pv[k] >> 26], 1);
            }
        }
    }
    __syncthreads();
    if (t < 64) {
        int v = cnt[t], inc = v;
#pragma unroll
        for (int mm = 1; mm < 64; mm <<= 1) {
            int u = __shfl_up(inc, mm, 64);
            if (t >= mm) inc += u;
        }
        loffs[t] = inc - v;
    }
    __syncthreads();
#pragma unroll
    for (int k = 0; k < 4; k++) {
        if (k < nv) {
            unsigned v = pv[k];
            int d6 = v >> 26;
            unsigned src = v & 0xFFFFu;
            float4 le = *(const float4*)(el + (size_t)src * 4);
            float4 re = fer[d6];
            float a0 = le.x + re.x, a1 = le.y + re.y;
            float a2 = le.z + re.z, a3 = le.w + re.w;
            a0 = fmaxf(a0, 0.01f * a0); a1 = fmaxf(a1, 0.01f * a1);
            a2 = fmaxf(a2, 0.01f * a2); a3 = fmaxf(a3, 0.01f * a3);
            float4 e4;
            e4.x = __expf(a0); e4.y = __expf(a1);
            e4.z = __expf(a2); e4.w = __expf(a3);
            sexp[loffs[d6] + rk[k]] = e4;
        }
    }
    __syncthreads();
    {
        const int ln  = t >> 4;
        const int l16 = t & 15;
        const int st  = loffs[ln];
        const int en  = st + cnt[ln];
        float4 sum; sum.x = 0.f; sum.y = 0.f; sum.z = 0.f; sum.w = 0.f;
        for (int j = st + l16; j < en; j += 16) {
            float4 e = sexp[j];
            sum.x += e.x; sum.y += e.y; sum.z += e.z; sum.w += e.w;
        }
#pragma unroll
        for (int mm = 1; mm < 16; mm <<= 1) {
            sum.x += __shfl_xor(sum.x, mm, 64);
            sum.y += __shfl_xor(sum.y, mm, 64);
            sum.z += __shfl_xor(sum.z, mm, 64);
            sum.w += __shfl_xor(sum.w, mm, 64);
        }
        int node = i * 64 + ln;
        if (l16 == 0 && node < N) {
            float4 re = fer[ln];
            float4 w0; w0.x = re.x; w0.y = (sum.x > 0.f) ? 1.0f / sum.x : 0.f;
                       w0.z = re.y; w0.w = (sum.y > 0.f) ? 1.0f / sum.y : 0.f;
            float4 w1; w1.x = re.z; w1.y = (sum.z > 0.f) ? 1.0f / sum.z : 0.f;
                       w1.z = re.w; w1.w = (sum.w > 0.f) ? 1.0f / sum.w : 0.f;
            *(float4*)(esv + (size_t)node * 8)     = w0;
            *(float4*)(esv + (size_t)node * 8 + 4) = w1;
        }
    }
}

// ------- K4: fine-sort (dst-ordered within node) + weight precompute + R5 gather -------
// Edges within each node's contiguous region are ordered by dst-quadrant
// (dst>>14) via a 256-key two-level scan. Phase 4 is the R5-proven cheap loop
// (one node per wave-iter, step-8 unroll-2, pad-to-8 zero slots) — waves sweep
// ascending dsts in near-lockstep, so concurrent reads cluster into a ~4MB
// window per time slice (R6's confirmed locality mechanism, no loop overhead).
__global__ __launch_bounds__(1024, 8) void k_gather(const unsigned* __restrict__ C,
                                                    const int* __restrict__ gcnt,
                                                    const float* __restrict__ el,
                                                    const float* __restrict__ esv,
                                                    const unsigned short* __restrict__ Zp16,
                                                    float* __restrict__ out, int N)
{
    __shared__ uint4  meta[FPAD];   // x = dst<<8 (row byte offset), y = w01, z = w23
    __shared__ float4 fel[64];
    __shared__ int cnt[256], loffs[256];
    __shared__ int nstart[64], ntot[64];
    const int i = blockIdx.x;
    const int t = threadIdx.x;
    int count = gcnt[i]; if (count > FCAP) count = FCAP;
    const unsigned* slab = C + (size_t)i * FCAP;
    if (t < 64) {
        int node = i * 64 + t;
        float4 e;
        if (node < N) e = *(const float4*)(el + (size_t)node * 4);
        else { e.x = 0.f; e.y = 0.f; e.z = 0.f; e.w = 0.f; }
        fel[t] = e;
    }
    if (t < 256) cnt[t] = 0;
    for (int j = t; j < FPAD; j += 1024) {
        uint4 zz; zz.x = 0; zz.y = 0; zz.z = 0; zz.w = 0;
        meta[j] = zz;
    }
    __syncthreads();
    // phase 1: single-pass rank+histogram over 256 (node, dst-quadrant) keys
    unsigned pv[4]; int rk[4], ky[4];
    int nv = 0;
    {
        int base = 4 * t;
        if (base < count) {
            nv = count - base; if (nv > 4) nv = 4;
            if (nv == 4) {
                uint4 u = *(const uint4*)(slab + base);
                pv[0] = u.x; pv[1] = u.y; pv[2] = u.z; pv[3] = u.w;
            } else {
#pragma unroll
                for (int k = 0; k < 4; k++) { if (k < nv) pv[k] = slab[base + k]; }
            }
#pragma unroll
            for (int k = 0; k < 4; k++) {
                if (k < nv) {
                    ky[k] = (int)(((pv[k] >> 26) << 2) | ((pv[k] & 0xFFFFu) >> 14));
                    rk[k] = atomicAdd(&cnt[ky[k]], 1);
                }
            }
        }
    }
    __syncthreads();
    // phase 2: two-level scan (wave 0). Node totals padded to 8 give region
    // starts; within-node quadrant offsets are EXACT (no per-quadrant padding).
    if (t < 64) {
        int b  = t * 4;
        int c0 = cnt[b], c1 = cnt[b + 1], c2 = cnt[b + 2], c3 = cnt[b + 3];
        int tn = c0 + c1 + c2 + c3;
        int pn = (tn + 7) & ~7;
        int inc = pn;
#pragma unroll
        for (int mm = 1; mm < 64; mm <<= 1) {
            int u = __shfl_up(inc, mm, 64);
            if (t >= mm) inc += u;
        }
        int ns = inc - pn;
        nstart[t] = ns;
        ntot[t]   = tn;
        loffs[b]     = ns;
        loffs[b + 1] = ns + c0;
        loffs[b + 2] = ns + c0 + c1;
        loffs[b + 3] = ns + c0 + c1 + c2;
    }
    __syncthreads();
    // phase 3: weight computation + scatter into meta (from registers)
#pragma unroll
    for (int k = 0; k < 4; k++) {
        if (k < nv) {
            unsigned v = pv[k];
            unsigned dst = v & 0xFFFFu;
            int p = loffs[ky[k]] + rk[k];
            float4 ed = fel[v >> 26];
            float4 e0 = *(const float4*)(esv + (size_t)dst * 8);
            float4 e1 = *(const float4*)(esv + (size_t)dst * 8 + 4);
            float a0 = ed.x + e0.x, a1 = ed.y + e0.z;
            float a2 = ed.z + e1.x, a3 = ed.w + e1.z;
            a0 = fmaxf(a0, 0.01f * a0); a1 = fmaxf(a1, 0.01f * a1);
            a2 = fmaxf(a2, 0.01f * a2); a3 = fmaxf(a3, 0.01f * a3);
            float t0 = __expf(a0) * e0.y;
            float t1 = __expf(a1) * e0.w;
            float t2 = __expf(a2) * e1.y;
            float t3 = __expf(a3) * e1.w;
            unsigned u0 = __float_as_uint(t0) + 0x8000u;
            unsigned u1 = __float_as_uint(t1) + 0x8000u;
            unsigned u2 = __float_as_uint(t2) + 0x8000u;
            unsigned u3 = __float_as_uint(t3) + 0x8000u;
            uint4 mr;
            mr.x = dst << 8;
            mr.y = (u0 >> 16) | (u1 & 0xffff0000u);
            mr.z = (u2 >> 16) | (u3 & 0xffff0000u);
            mr.w = 0;
            meta[p] = mr;
        }
    }
    __syncthreads();
    // phase 4: R5 single-stream quarter-wave gather; wave w -> nodes w*4..w*4+3
    const int wave = t >> 6;
    const int q    = (t >> 4) & 3;
    const int m    = t & 15;
    const unsigned vm = (unsigned)m * 16u;
    const char* zb = (const char*)Zp16;
#define GB(ACC, J) { \
        uint4 mu = meta[(J)]; \
        uint4 z  = *(const uint4*)(zb + (size_t)(mu.x + vm)); \
        float wxl = __uint_as_float(mu.y << 16); \
        float wxh = __uint_as_float(mu.y & 0xffff0000u); \
        float wyl = __uint_as_float(mu.z << 16); \
        float wyh = __uint_as_float(mu.z & 0xffff0000u); \
        ACC[0] = fmaf(wxl, __uint_as_float(z.x << 16),         ACC[0]); \
        ACC[1] = fmaf(wxh, __uint_as_float(z.x & 0xffff0000u), ACC[1]); \
        ACC[2] = fmaf(wyl, __uint_as_float(z.y << 16),         ACC[2]); \
        ACC[3] = fmaf(wyh, __uint_as_float(z.y & 0xffff0000u), ACC[3]); \
        ACC[4] = fmaf(wxl, __uint_as_float(z.z << 16),         ACC[4]); \
        ACC[5] = fmaf(wxh, __uint_as_float(z.z & 0xffff0000u), ACC[5]); \
        ACC[6] = fmaf(wyl, __uint_as_float(z.w << 16),         ACC[6]); \
        ACC[7] = fmaf(wyh, __uint_as_float(z.w & 0xffff0000u), ACC[7]); \
    }
    for (int k = 0; k < 4; k++) {
        int ln   = wave * 4 + k;
        int node = i * 64 + ln;
        if (node >= N) break;
        const int st = nstart[ln];
        const int en = st + ((ntot[ln] + 7) & ~7);
        float acc[8];
#pragma unroll
        for (int rr = 0; rr < 8; rr++) acc[rr] = 0.f;
        for (int j = st + q; j < en; j += 8) {
            GB(acc, j);
            GB(acc, j + 4);
        }
#pragma unroll
        for (int rr = 0; rr < 8; rr++) {
            acc[rr] += __shfl_xor(acc[rr], 16, 64);
            acc[rr] += __shfl_xor(acc[rr], 32, 64);
        }
        if (q == 0) {
            float4 r0; r0.x = acc[0]; r0.y = acc[1]; r0.z = acc[2]; r0.w = acc[3];
            float4 r1; r1.x = acc[4]; r1.y = acc[5]; r1.z = acc[6]; r1.w = acc[7];
            float4* dp = (float4*)(out + (size_t)node * CH + m * 8);
            dp[0] = r0; dp[1] = r1;
        }
    }
#undef GB
}

static inline char* align16(char* p) {
    return (char*)(((uintptr_t)p + 15) & ~(uintptr_t)15);
}

extern "C" void kernel_launch(void* const* d_in, const int* in_sizes, int n_in,
                              void* d_out, int out_size, void* d_ws, size_t ws_size,
                              hipStream_t stream)
{
    const int*   idx = (const int*)d_in[0];
    const float* Z   = (const float*)d_in[2];
    const float* W   = (const float*)d_in[3];
    const float* b   = (const float*)d_in[4];
    const float* al  = (const float*)d_in[5];
    const float* ar  = (const float*)d_in[6];
    float* out = (float*)d_out;

    const int E = in_sizes[0] / 2;
    const int N = in_sizes[2] / KIN;
    const int NBK = (N + 63) >> 6;      // 64-node buckets (<= 1024)

    char* p = (char*)d_ws;
    unsigned short* Zp16 = (unsigned short*)p;  p = align16(p + sizeof(unsigned short) * (size_t)N * CH);
    float* el  = (float*)p;              p = align16(p + sizeof(float) * (size_t)N * 4);
    float* er  = (float*)p;              p = align16(p + sizeof(float) * (size_t)N * 4);
    float* esv = (float*)p;              p = align16(p + sizeof(float) * (size_t)N * 8);
    int* gcnt  = (int*)p;                p = align16(p + sizeof(int) * (size_t)2 * NBK);
    unsigned* C = (unsigned*)p;          p = align16(p + sizeof(unsigned) * (size_t)2 * NBK * FCAP);

    k_gemm  <<<NBK, 256, 0, stream>>>(Z, W, b, al, ar, Zp16, el, er, gcnt, N, NBK);
    k_bucket<<<(E + EB - 1) / EB, 1024, 0, stream>>>(idx, gcnt, C, E, NBK);
    k_soft  <<<NBK, 1024, 0, stream>>>(C, gcnt, el, er, esv, N, NBK);
    k_gather<<<NBK, 1024, 0, stream>>>(C, gcnt, el, esv, Zp16, out, N);
}

// Round 9
// 205.480 us; speedup vs baseline: 1.1635x; 1.0136x over previous
//
#include <hip/hip_runtime.h>
#include <hip/hip_bf16.h>
#include <math.h>

#define CH 128      // OUT_SIZE * HEADS
#define KIN 128     // IN_SIZE
#define FCAP 2560   // slab slots per 64-node bucket (mean 2048 +- 45, 11 sigma headroom)
#define FPAD 3072   // FCAP + 64 nodes * 7 max pad (448) -> 3008 <= 3072
#define EB 8192     // edges per k_bucket block (196 blocks; R4-proven best)

typedef __attribute__((ext_vector_type(8))) short short8;   // 8 bf16 (4 VGPRs)
typedef __attribute__((ext_vector_type(4))) float f32x4;    // MFMA acc

__device__ __forceinline__ unsigned short f2bf(float x) {
    __hip_bfloat16 h = __float2bfloat16(x);
    return *reinterpret_cast<unsigned short*>(&h);
}

// ------- K1: MFMA gemm: Zp16 = bf16(Z @ W^T + b), fused el/er epilogue -------
// Also zeroes gcnt (block 0) so no separate memset dispatch is needed.
#define AS 136   // padded LDS stride (halfwords) per row
__global__ __launch_bounds__(256) void k_gemm(const float* __restrict__ Z,
                                              const float* __restrict__ W,
                                              const float* __restrict__ b,
                                              const float* __restrict__ al,
                                              const float* __restrict__ ar,
                                              unsigned short* __restrict__ Zp16,
                                              float* __restrict__ el,
                                              float* __restrict__ er,
                                              int* __restrict__ gcnt,
                                              int N, int NBK)
{
    __shared__ unsigned short lA[64 * AS];
    __shared__ unsigned short lB[128 * AS];
    const int tid = threadIdx.x;
    const int nb0 = blockIdx.x * 64;

    if (blockIdx.x == 0) {
        for (int i = tid; i < 2 * NBK; i += 256) gcnt[i] = 0;
    }

#pragma unroll
    for (int i = 0; i < 8; i++) {
        int slot = tid + i * 256;
        int row  = slot >> 5;
        int kq   = (slot & 31) * 4;
        int gn   = nb0 + row; if (gn >= N) gn = N - 1;
        float4 v = *(const float4*)(Z + (size_t)gn * KIN + kq);
        unsigned lo = ((unsigned)f2bf(v.y) << 16) | f2bf(v.x);
        unsigned hi = ((unsigned)f2bf(v.w) << 16) | f2bf(v.z);
        uint2 pk; pk.x = lo; pk.y = hi;
        *(uint2*)(&lA[row * AS + kq]) = pk;
    }
#pragma unroll
    for (int i = 0; i < 16; i++) {
        int slot = tid + i * 256;
        int n    = slot >> 5;
        int kq   = (slot & 31) * 4;
        float4 v = *(const float4*)(W + (size_t)n * KIN + kq);
        unsigned lo = ((unsigned)f2bf(v.y) << 16) | f2bf(v.x);
        unsigned hi = ((unsigned)f2bf(v.w) << 16) | f2bf(v.z);
        uint2 pk; pk.x = lo; pk.y = hi;
        *(uint2*)(&lB[n * AS + kq]) = pk;
    }
    __syncthreads();

    const int wv   = tid >> 6;
    const int lane = tid & 63;
    const int r16  = lane & 15;
    const int quad = lane >> 4;

    f32x4 acc[8];
#pragma unroll
    for (int t = 0; t < 8; t++) { acc[t][0] = 0.f; acc[t][1] = 0.f; acc[t][2] = 0.f; acc[t][3] = 0.f; }

    const unsigned short* pa = lA + (wv * 16 + r16) * AS;
#pragma unroll
    for (int kk = 0; kk < 4; kk++) {
        short8 af = *(const short8*)(pa + kk * 32 + quad * 8);
#pragma unroll
        for (int t = 0; t < 8; t++) {
            short8 bf = *(const short8*)(lB + (16 * t + r16) * AS + kk * 32 + quad * 8);
            acc[t] = __builtin_amdgcn_mfma_f32_16x16x32_bf16(af, bf, acc[t], 0, 0, 0);
        }
    }

    float bias[8], alv[8], arv[8];
#pragma unroll
    for (int t = 0; t < 8; t++) {
        bias[t] = b[16 * t + r16];
        alv[t]  = al[16 * t + r16];
        arv[t]  = ar[16 * t + r16];
    }
#pragma unroll
    for (int t = 0; t < 8; t++) {
#pragma unroll
        for (int reg = 0; reg < 4; reg++) acc[t][reg] += bias[t];
    }

    float ev[4], rv[4];
#pragma unroll
    for (int reg = 0; reg < 4; reg++) {
        float se = 0.f, sr = 0.f;
#pragma unroll
        for (int t = 0; t < 8; t++) { se += acc[t][reg] * alv[t]; sr += acc[t][reg] * arv[t]; }
        se += __shfl_xor(se, 4, 64); se += __shfl_xor(se, 8, 64);
        sr += __shfl_xor(sr, 4, 64); sr += __shfl_xor(sr, 8, 64);
        ev[reg] = se; rv[reg] = sr;
    }
    if (r16 < 4) {
        int h = r16;
#pragma unroll
        for (int reg = 0; reg < 4; reg++) {
            int gn = nb0 + wv * 16 + quad * 4 + reg;
            if (gn < N) {
                el[(size_t)gn * 4 + h] = ev[reg];
                er[(size_t)gn * 4 + h] = rv[reg];
            }
        }
    }

    __syncthreads();
#pragma unroll
    for (int t = 0; t < 8; t++) {
#pragma unroll
        for (int reg = 0; reg < 4; reg++) {
            int rrow = wv * 16 + quad * 4 + reg;
            lA[rrow * AS + 16 * t + r16] = f2bf(acc[t][reg]);
        }
    }
    __syncthreads();
    {
        int row  = tid >> 2;
        int col0 = (tid & 3) * 32;
        int gn   = nb0 + row;
        if (gn < N) {
            const unsigned short* sp = lA + row * AS + col0;
            uint4 v0 = *(const uint4*)(sp);
            uint4 v1 = *(const uint4*)(sp + 8);
            uint4 v2 = *(const uint4*)(sp + 16);
            uint4 v3 = *(const uint4*)(sp + 24);
            uint4* dp = (uint4*)(Zp16 + (size_t)gn * CH + col0);
            dp[0] = v0; dp[1] = v1; dp[2] = v2; dp[3] = v3;
        }
    }
}

// ------- K2: dual-side bucket scatter, single pass (8 edges/thread in registers) -------
// payload: (node&63)<<26 | other_node ; slab for (side,bucket) i at C[i*FCAP ...]
__global__ __launch_bounds__(1024) void k_bucket(const int* __restrict__ idx,
                                                 int* __restrict__ gcnt,
                                                 unsigned* __restrict__ C,
                                                 int E, int NBK)
{
    __shared__ int cnt[2048];
    __shared__ int lbase[2048];
    const int t = threadIdx.x;
    const int nb2 = 2 * NBK;
    for (int i = t; i < nb2; i += 1024) cnt[i] = 0;
    __syncthreads();
    const int lo = blockIdx.x * EB;
    const int hi = min(lo + EB, E);

    int s[8], d[8], rs[8], rd[8];
    int nv = 0;
    {
        int base = lo + 8 * t;
        if (base < hi) {
            nv = hi - base; if (nv > 8) nv = 8;
            if (nv == 8) {
                int4 sa = *(const int4*)(idx + base);
                int4 sb = *(const int4*)(idx + base + 4);
                int4 da = *(const int4*)(idx + E + base);
                int4 db = *(const int4*)(idx + E + base + 4);
                s[0] = sa.x; s[1] = sa.y; s[2] = sa.z; s[3] = sa.w;
                s[4] = sb.x; s[5] = sb.y; s[6] = sb.z; s[7] = sb.w;
                d[0] = da.x; d[1] = da.y; d[2] = da.z; d[3] = da.w;
                d[4] = db.x; d[5] = db.y; d[6] = db.z; d[7] = db.w;
            } else {
#pragma unroll
                for (int k = 0; k < 8; k++) {
                    if (k < nv) { s[k] = idx[base + k]; d[k] = idx[E + base + k]; }
                }
            }
#pragma unroll
            for (int k = 0; k < 8; k++) {
                if (k < nv) {
                    rs[k] = atomicAdd(&cnt[s[k] >> 6], 1);
                    rd[k] = atomicAdd(&cnt[NBK + (d[k] >> 6)], 1);
                }
            }
        }
    }
    __syncthreads();
    for (int i = t; i < nb2; i += 1024) {
        int v = cnt[i];
        lbase[i] = v ? atomicAdd(&gcnt[i], v) : 0;
    }
    __syncthreads();
#pragma unroll
    for (int k = 0; k < 8; k++) {
        if (k < nv) {
            int bs = s[k] >> 6;
            int p  = lbase[bs] + rs[k];
            if (p < FCAP)
                C[(size_t)bs * FCAP + p] = ((unsigned)(s[k] & 63) << 26) | (unsigned)d[k];
            int bd = NBK + (d[k] >> 6);
            p = lbase[bd] + rd[k];
            if (p < FCAP)
                C[(size_t)bd * FCAP + p] = ((unsigned)(d[k] & 63) << 26) | (unsigned)s[k];
        }
    }
}

// ------- K3: dst-side softmax denominators via sort + segmented reduce (no atomics) -------
// Output esv[node*8] = (er0, 1/s0, er1, 1/s1, er2, 1/s2, er3, 1/s3).
__global__ __launch_bounds__(1024) void k_soft(const unsigned* __restrict__ C,
                                               const int* __restrict__ gcnt,
                                               const float* __restrict__ el,
                                               const float* __restrict__ er,
                                               float* __restrict__ esv, int N, int NBK)
{
    __shared__ float4 sexp[FCAP];   // 40 KB
    __shared__ float4 fer[64];
    __shared__ int cnt[64], loffs[64];
    const int i = blockIdx.x;
    const int t = threadIdx.x;
    int count = gcnt[NBK + i]; if (count > FCAP) count = FCAP;
    const unsigned* slab = C + (size_t)(NBK + i) * FCAP;
    if (t < 64) {
        cnt[t] = 0;
        int node = i * 64 + t;
        float4 e;
        if (node < N) e = *(const float4*)(er + (size_t)node * 4);
        else { e.x = 0.f; e.y = 0.f; e.z = 0.f; e.w = 0.f; }
        fer[t] = e;
    }
    __syncthreads();
    unsigned pv[4]; int rk[4];
    int nv = 0;
    {
        int base = 4 * t;
        if (base < count) {
            nv = count - base; if (nv > 4) nv = 4;
            if (nv == 4) {
                uint4 u = *(const uint4*)(slab + base);
                pv[0] = u.x; pv[1] = u.y; pv[2] = u.z; pv[3] = u.w;
            } else {
#pragma unroll
                for (int k = 0; k < 4; k++) { if (k < nv) pv[k] = slab[base + k]; }
            }
#pragma unroll
            for (int k = 0; k < 4; k++) {
                if (k < nv) rk[k] = atomicAdd(&cnt[pv[k] >> 26], 1);
            }
        }
    }
    __syncthreads();
    if (t < 64) {
        int v = cnt[t], inc = v;
#pragma unroll
        for (int mm = 1; mm < 64; mm <<= 1) {
            int u = __shfl_up(inc, mm, 64);
            if (t >= mm) inc += u;
        }
        loffs[t] = inc - v;
    }
    __syncthreads();
#pragma unroll
    for (int k = 0; k < 4; k++) {
        if (k < nv) {
            unsigned v = pv[k];
            int d6 = v >> 26;
            unsigned src = v & 0xFFFFu;
            float4 le = *(const float4*)(el + (size_t)src * 4);
            float4 re = fer[d6];
            float a0 = le.x + re.x, a1 = le.y + re.y;
            float a2 = le.z + re.z, a3 = le.w + re.w;
            a0 = fmaxf(a0, 0.01f * a0); a1 = fmaxf(a1, 0.01f * a1);
            a2 = fmaxf(a2, 0.01f * a2); a3 = fmaxf(a3, 0.01f * a3);
            float4 e4;
            e4.x = __expf(a0); e4.y = __expf(a1);
            e4.z = __expf(a2); e4.w = __expf(a3);
            sexp[loffs[d6] + rk[k]] = e4;
        }
    }
    __syncthreads();
    {
        const int ln  = t >> 4;
        const int l16 = t & 15;
        const int st  = loffs[ln];
        const int en  = st + cnt[ln];
        float4 sum; sum.x = 0.f; sum.y = 0.f; sum.z = 0.f; sum.w = 0.f;
        for (int j = st + l16; j < en; j += 16) {
            float4 e = sexp[j];
            sum.x += e.x; sum.y += e.y; sum.z += e.z; sum.w += e.w;
        }
#pragma unroll
        for (int mm = 1; mm < 16; mm <<= 1) {
            sum.x += __shfl_xor(sum.x, mm, 64);
            sum.y += __shfl_xor(sum.y, mm, 64);
            sum.z += __shfl_xor(sum.z, mm, 64);
            sum.w += __shfl_xor(sum.w, mm, 64);
        }
        int node = i * 64 + ln;
        if (l16 == 0 && node < N) {
            float4 re = fer[ln];
            float4 w0; w0.x = re.x; w0.y = (sum.x > 0.f) ? 1.0f / sum.x : 0.f;
                       w0.z = re.y; w0.w = (sum.y > 0.f) ? 1.0f / sum.y : 0.f;
            float4 w1; w1.x = re.z; w1.y = (sum.z > 0.f) ? 1.0f / sum.z : 0.f;
                       w1.z = re.w; w1.w = (sum.w > 0.f) ? 1.0f / sum.w : 0.f;
            *(float4*)(esv + (size_t)node * 8)     = w0;
            *(float4*)(esv + (size_t)node * 8 + 4) = w1;
        }
    }
}

// ------- K4: fine-sort + weight precompute + depth-2 pipelined quarter-wave gather -------
// Phase 4: single-node stream with explicit depth-2 rotate: issue next pair's
// meta+z loads BEFORE consuming current pair (~4 loads in flight per lane).
// Prefetch indices j+8/j+12 stay < FPAD (en <= 3008), and every meta slot —
// pad or neighbor — carries a valid in-array row offset, so the speculative
// load is always address-safe; unconsumed values are simply discarded.
// launch_bounds(1024,7): VGPR cap 73 (need ~60; R4's failure was the 64 cap).
__global__ __launch_bounds__(1024, 7) void k_gather(const unsigned* __restrict__ C,
                                                    const int* __restrict__ gcnt,
                                                    const float* __restrict__ el,
                                                    const float* __restrict__ esv,
                                                    const unsigned short* __restrict__ Zp16,
                                                    float* __restrict__ out, int N)
{
    __shared__ uint4  meta[FPAD];   // x = dst<<8 (row byte offset), y = w01, z = w23
    __shared__ float4 fel[64];
    __shared__ int cnt[256], loffs[256];
    __shared__ int nstart[64], ntot[64];
    const int i = blockIdx.x;
    const int t = threadIdx.x;
    int count = gcnt[i]; if (count > FCAP) count = FCAP;
    const unsigned* slab = C + (size_t)i * FCAP;
    if (t < 64) {
        int node = i * 64 + t;
        float4 e;
        if (node < N) e = *(const float4*)(el + (size_t)node * 4);
        else { e.x = 0.f; e.y = 0.f; e.z = 0.f; e.w = 0.f; }
        fel[t] = e;
    }
    if (t < 256) cnt[t] = 0;
    for (int j = t; j < FPAD; j += 1024) {
        uint4 zz; zz.x = 0; zz.y = 0; zz.z = 0; zz.w = 0;
        meta[j] = zz;
    }
    __syncthreads();
    // phase 1: single-pass rank+histogram over 256 (node, dst-quadrant) keys
    unsigned pv[4]; int rk[4], ky[4];
    int nv = 0;
    {
        int base = 4 * t;
        if (base < count) {
            nv = count - base; if (nv > 4) nv = 4;
            if (nv == 4) {
                uint4 u = *(const uint4*)(slab + base);
                pv[0] = u.x; pv[1] = u.y; pv[2] = u.z; pv[3] = u.w;
            } else {
#pragma unroll
                for (int k = 0; k < 4; k++) { if (k < nv) pv[k] = slab[base + k]; }
            }
#pragma unroll
            for (int k = 0; k < 4; k++) {
                if (k < nv) {
                    ky[k] = (int)(((pv[k] >> 26) << 2) | ((pv[k] & 0xFFFFu) >> 14));
                    rk[k] = atomicAdd(&cnt[ky[k]], 1);
                }
            }
        }
    }
    __syncthreads();
    // phase 2: two-level scan (wave 0); node totals padded to 8
    if (t < 64) {
        int b  = t * 4;
        int c0 = cnt[b], c1 = cnt[b + 1], c2 = cnt[b + 2], c3 = cnt[b + 3];
        int tn = c0 + c1 + c2 + c3;
        int pn = (tn + 7) & ~7;
        int inc = pn;
#pragma unroll
        for (int mm = 1; mm < 64; mm <<= 1) {
            int u = __shfl_up(inc, mm, 64);
            if (t >= mm) inc += u;
        }
        int ns = inc - pn;
        nstart[t] = ns;
        ntot[t]   = tn;
        loffs[b]     = ns;
        loffs[b + 1] = ns + c0;
        loffs[b + 2] = ns + c0 + c1;
        loffs[b + 3] = ns + c0 + c1 + c2;
    }
    __syncthreads();
    // phase 3: weight computation + scatter into meta (from registers)
#pragma unroll
    for (int k = 0; k < 4; k++) {
        if (k < nv) {
            unsigned v = pv[k];
            unsigned dst = v & 0xFFFFu;
            int p = loffs[ky[k]] + rk[k];
            float4 ed = fel[v >> 26];
            float4 e0 = *(const float4*)(esv + (size_t)dst * 8);
            float4 e1 = *(const float4*)(esv + (size_t)dst * 8 + 4);
            float a0 = ed.x + e0.x, a1 = ed.y + e0.z;
            float a2 = ed.z + e1.x, a3 = ed.w + e1.z;
            a0 = fmaxf(a0, 0.01f * a0); a1 = fmaxf(a1, 0.01f * a1);
            a2 = fmaxf(a2, 0.01f * a2); a3 = fmaxf(a3, 0.01f * a3);
            float t0 = __expf(a0) * e0.y;
            float t1 = __expf(a1) * e0.w;
            float t2 = __expf(a2) * e1.y;
            float t3 = __expf(a3) * e1.w;
            unsigned u0 = __float_as_uint(t0) + 0x8000u;
            unsigned u1 = __float_as_uint(t1) + 0x8000u;
            unsigned u2 = __float_as_uint(t2) + 0x8000u;
            unsigned u3 = __float_as_uint(t3) + 0x8000u;
            uint4 mr;
            mr.x = dst << 8;
            mr.y = (u0 >> 16) | (u1 & 0xffff0000u);
            mr.z = (u2 >> 16) | (u3 & 0xffff0000u);
            mr.w = 0;
            meta[p] = mr;
        }
    }
    __syncthreads();
    // phase 4: depth-2 pipelined quarter-wave gather; wave w -> nodes w*4..w*4+3
    const int wave = t >> 6;
    const int q    = (t >> 4) & 3;
    const int m    = t & 15;
    const unsigned vm = (unsigned)m * 16u;
    const char* zb = (const char*)Zp16;
#define CONS(ACC, MU, ZZ) { \
        float wxl = __uint_as_float(MU.y << 16); \
        float wxh = __uint_as_float(MU.y & 0xffff0000u); \
        float wyl = __uint_as_float(MU.z << 16); \
        float wyh = __uint_as_float(MU.z & 0xffff0000u); \
        ACC[0] = fmaf(wxl, __uint_as_float(ZZ.x << 16),         ACC[0]); \
        ACC[1] = fmaf(wxh, __uint_as_float(ZZ.x & 0xffff0000u), ACC[1]); \
        ACC[2] = fmaf(wyl, __uint_as_float(ZZ.y << 16),         ACC[2]); \
        ACC[3] = fmaf(wyh, __uint_as_float(ZZ.y & 0xffff0000u), ACC[3]); \
        ACC[4] = fmaf(wxl, __uint_as_float(ZZ.z << 16),         ACC[4]); \
        ACC[5] = fmaf(wxh, __uint_as_float(ZZ.z & 0xffff0000u), ACC[5]); \
        ACC[6] = fmaf(wyl, __uint_as_float(ZZ.w << 16),         ACC[6]); \
        ACC[7] = fmaf(wyh, __uint_as_float(ZZ.w & 0xffff0000u), ACC[7]); \
    }
    for (int k = 0; k < 4; k++) {
        int ln   = wave * 4 + k;
        int node = i * 64 + ln;
        if (node >= N) break;
        const int st = nstart[ln];
        const int en = st + ((ntot[ln] + 7) & ~7);
        float acc[8];
#pragma unroll
        for (int rr = 0; rr < 8; rr++) acc[rr] = 0.f;
        int j = st + q;
        if (j < en) {
            uint4 m0 = meta[j];
            uint4 z0 = *(const uint4*)(zb + (size_t)(m0.x + vm));
            uint4 m1 = meta[j + 4];
            uint4 z1 = *(const uint4*)(zb + (size_t)(m1.x + vm));
            for (; j + 8 < en; j += 8) {
                uint4 mA = meta[j + 8];
                uint4 zA = *(const uint4*)(zb + (size_t)(mA.x + vm));
                uint4 mB = meta[j + 12];
                uint4 zB = *(const uint4*)(zb + (size_t)(mB.x + vm));
                CONS(acc, m0, z0);
                CONS(acc, m1, z1);
                m0 = mA; z0 = zA; m1 = mB; z1 = zB;
            }
            CONS(acc, m0, z0);
            CONS(acc, m1, z1);
        }
#pragma unroll
        for (int rr = 0; rr < 8; rr++) {
            acc[rr] += __shfl_xor(acc[rr], 16, 64);
            acc[rr] += __shfl_xor(acc[rr], 32, 64);
        }
        if (q == 0) {
            float4 r0; r0.x = acc[0]; r0.y = acc[1]; r0.z = acc[2]; r0.w = acc[3];
            float4 r1; r1.x = acc[4]; r1.y = acc[5]; r1.z = acc[6]; r1.w = acc[7];
            float4* dp = (float4*)(out + (size_t)node * CH + m * 8);
            dp[0] = r0; dp[1] = r1;
        }
    }
#undef CONS
}

static inline char* align16(char* p) {
    return (char*)(((uintptr_t)p + 15) & ~(uintptr_t)15);
}

extern "C" void kernel_launch(void* const* d_in, const int* in_sizes, int n_in,
                              void* d_out, int out_size, void* d_ws, size_t ws_size,
                              hipStream_t stream)
{
    const int*   idx = (const int*)d_in[0];
    const float* Z   = (const float*)d_in[2];
    const float* W   = (const float*)d_in[3];
    const float* b   = (const float*)d_in[4];
    const float* al  = (const float*)d_in[5];
    const float* ar  = (const float*)d_in[6];
    float* out = (float*)d_out;

    const int E = in_sizes[0] / 2;
    const int N = in_sizes[2] / KIN;
    const int NBK = (N + 63) >> 6;      // 64-node buckets (<= 1024)

    char* p = (char*)d_ws;
    unsigned short* Zp16 = (unsigned short*)p;  p = align16(p + sizeof(unsigned short) * (size_t)N * CH);
    float* el  = (float*)p;              p = align16(p + sizeof(float) * (size_t)N * 4);
    float* er  = (float*)p;              p = align16(p + sizeof(float) * (size_t)N * 4);
    float* esv = (float*)p;              p = align16(p + sizeof(float) * (size_t)N * 8);
    int* gcnt  = (int*)p;                p = align16(p + sizeof(int) * (size_t)2 * NBK);
    unsigned* C = (unsigned*)p;          p = align16(p + sizeof(unsigned) * (size_t)2 * NBK * FCAP);

    k_gemm  <<<NBK, 256, 0, stream>>>(Z, W, b, al, ar, Zp16, el, er, gcnt, N, NBK);
    k_bucket<<<(E + EB - 1) / EB, 1024, 0, stream>>>(idx, gcnt, C, E, NBK);
    k_soft  <<<NBK, 1024, 0, stream>>>(C, gcnt, el, er, esv, N, NBK);
    k_gather<<<NBK, 1024, 0, stream>>>(C, gcnt, el, esv, Zp16, out, N);
}